// Round 1
// baseline (453.708 us; speedup 1.0000x reference)
//
#include <hip/hip_runtime.h>
#include <cstdint>
#include <cstddef>

using bf16   = __bf16;
using bf16x8 = __bf16 __attribute__((ext_vector_type(8)));
using f32x4  = float  __attribute__((ext_vector_type(4)));
using u16    = unsigned short;

#define MFMA16(a, b, c) __builtin_amdgcn_mfma_f32_16x16x32_bf16(a, b, c, 0, 0, 0)

__device__ __forceinline__ u16 f2bf(float f) {
  union { float f; unsigned u; } v; v.f = f;
  unsigned r = v.u + 0x7fffu + ((v.u >> 16) & 1u);
  return (u16)(r >> 16);
}
__device__ __forceinline__ bf16x8 ldb8(const u16* p) { return *(const bf16x8*)p; }
__device__ __forceinline__ float red_max16(float v) {
  v = fmaxf(v, __shfl_xor(v, 1, 64)); v = fmaxf(v, __shfl_xor(v, 2, 64));
  v = fmaxf(v, __shfl_xor(v, 4, 64)); v = fmaxf(v, __shfl_xor(v, 8, 64));
  return v;
}
__device__ __forceinline__ float red_sum16(float v) {
  v += __shfl_xor(v, 1, 64); v += __shfl_xor(v, 2, 64);
  v += __shfl_xor(v, 4, 64); v += __shfl_xor(v, 8, 64);
  return v;
}

// ---------- prep: weight convert / transpose to bf16 [n][k] ----------
__global__ void k_transpose_cvt(const float* __restrict__ src, u16* __restrict__ dst, int K, int N) {
  int idx = blockIdx.x * 256 + threadIdx.x;
  if (idx >= K * N) return;
  int n = idx / K, k = idx - n * K;           // consecutive idx -> consecutive k: coalesced writes
  dst[idx] = f2bf(src[(size_t)k * N + n]);
}
__global__ void k_cvt(const float* __restrict__ src, u16* __restrict__ dst, int n) {
  int idx = blockIdx.x * 256 + threadIdx.x;
  if (idx < n) dst[idx] = f2bf(src[idx]);
}

// ---------- MLP layer 1: T1[r][j] = leaky(LN(x[r]*w1[j]+b1[j])), j<128 ----------
__global__ __launch_bounds__(256) void k_mlp1(const float* __restrict__ x, const float* __restrict__ w1,
    const float* __restrict__ b1, const float* __restrict__ g, const float* __restrict__ bb,
    u16* __restrict__ T1) {
  int lane = threadIdx.x & 63;
  int r = blockIdx.x * 4 + (threadIdx.x >> 6);   // one wave per row
  float xv = x[r];
  float t0 = xv * w1[lane] + b1[lane];
  float t1 = xv * w1[lane + 64] + b1[lane + 64];
  float s = t0 + t1;
  #pragma unroll
  for (int m = 1; m <= 32; m <<= 1) s += __shfl_xor(s, m, 64);
  float mu = s * (1.f / 128.f);
  float d0 = t0 - mu, d1 = t1 - mu;
  float vv = d0 * d0 + d1 * d1;
  #pragma unroll
  for (int m = 1; m <= 32; m <<= 1) vv += __shfl_xor(vv, m, 64);
  float inv = rsqrtf(vv * (1.f / 128.f) + 1e-5f);
  float o0 = d0 * inv * g[lane] + bb[lane];
  float o1 = d1 * inv * g[lane + 64] + bb[lane + 64];
  o0 = o0 > 0.f ? o0 : 0.01f * o0;
  o1 = o1 > 0.f ? o1 : 0.01f * o1;
  T1[(size_t)r * 128 + lane]      = f2bf(o0);
  T1[(size_t)r * 128 + lane + 64] = f2bf(o1);
}

// ---------- GEMM (M=16384, N=256) + bias + LayerNorm(row) + leaky ----------
// A [M][K] bf16 row-major (k-contig), Bt [256][K] bf16 (n-rows, k-contig).
template<int K, int NC>
__global__ __launch_bounds__(256) void k_gemm_ln(const u16* __restrict__ A, const u16* __restrict__ Bt,
    const float* __restrict__ bias, const float* __restrict__ g, const float* __restrict__ bb,
    u16* __restrict__ out) {
  constexpr int LD = K + 8;     // +16B pad: 2-way bank conflicts only, keeps 16B align
  constexpr int CPR = K / 8;    // 16B chunks per row
  __shared__ u16 sA[64 * LD];
  __shared__ u16 sB[NC * LD];
  int tid = threadIdx.x, w = tid >> 6, lane = tid & 63, quad = lane >> 4, l16 = lane & 15;
  int i0 = blockIdx.x * 64;
  // stage A tile (full K)
  #pragma unroll
  for (int p = 0; p < (64 * CPR) / 256; ++p) {
    int q = p * 256 + tid; int row = q / CPR, c8 = q - row * CPR;
    *(uint4*)(sA + row * LD + c8 * 8) = *(const uint4*)(A + (size_t)(i0 + row) * K + c8 * 8);
  }
  f32x4 z = {0.f, 0.f, 0.f, 0.f};
  f32x4 acc[16];
  #pragma unroll
  for (int f = 0; f < 16; ++f) acc[f] = z;
  bf16x8 af[K / 32];
  constexpr int NCH = 256 / NC;
  for (int nc = 0; nc < NCH; ++nc) {
    if (nc) __syncthreads();
    #pragma unroll
    for (int p = 0; p < (NC * CPR) / 256; ++p) {
      int q = p * 256 + tid; int row = q / CPR, c8 = q - row * CPR;
      *(uint4*)(sB + row * LD + c8 * 8) = *(const uint4*)(Bt + (size_t)(nc * NC + row) * K + c8 * 8);
    }
    __syncthreads();
    if (nc == 0) {
      #pragma unroll
      for (int kk = 0; kk < K / 32; ++kk) af[kk] = ldb8(sA + (w * 16 + l16) * LD + kk * 32 + quad * 8);
    }
    #pragma unroll
    for (int nb = 0; nb < NC / 16; ++nb) {
      int f = nc * (NC / 16) + nb;
      #pragma unroll
      for (int kk = 0; kk < K / 32; ++kk) {
        bf16x8 bfr = ldb8(sB + (nb * 16 + l16) * LD + kk * 32 + quad * 8);
        acc[f] = MFMA16(af[kk], bfr, acc[f]);
      }
    }
  }
  // epilogue: +bias, LN over 256 cols, leaky, bf16 store
  #pragma unroll
  for (int f = 0; f < 16; ++f) {
    float bv = bias[f * 16 + l16];
    acc[f][0] += bv; acc[f][1] += bv; acc[f][2] += bv; acc[f][3] += bv;
  }
  #pragma unroll
  for (int r = 0; r < 4; ++r) {
    float s = 0;
    #pragma unroll
    for (int f = 0; f < 16; ++f) s += acc[f][r];
    s = red_sum16(s);
    float mu = s * (1.f / 256.f);
    float vv = 0;
    #pragma unroll
    for (int f = 0; f < 16; ++f) { float d = acc[f][r] - mu; vv += d * d; }
    vv = red_sum16(vv);
    float inv = rsqrtf(vv * (1.f / 256.f) + 1e-5f);
    int rowg = i0 + w * 16 + quad * 4 + r;
    #pragma unroll
    for (int f = 0; f < 16; ++f) {
      int col = f * 16 + l16;
      float o = (acc[f][r] - mu) * inv * g[col] + bb[col];
      o = o > 0.f ? o : 0.01f * o;
      out[(size_t)rowg * 256 + col] = f2bf(o);
    }
  }
}

// ---------- MLP layer 4: GEMM + silu, split into K [b][d][c] and V^T [b][c][d] ----------
__global__ __launch_bounds__(256) void k_gemm_silu(const u16* __restrict__ A, const u16* __restrict__ Bt,
    const float* __restrict__ bias, u16* __restrict__ Kb, u16* __restrict__ Vt) {
  constexpr int LD = 264, CPR = 32, NC = 32;
  __shared__ u16 sA[64 * LD];
  __shared__ u16 sB[NC * LD];
  int tid = threadIdx.x, w = tid >> 6, lane = tid & 63, quad = lane >> 4, l16 = lane & 15;
  int i0 = blockIdx.x * 64;
  int half = blockIdx.y;   // 0: K-half (cols 0..255), 1: V-half (cols 256..511)
  #pragma unroll
  for (int p = 0; p < 8; ++p) {
    int q = p * 256 + tid; int row = q >> 5, c8 = q & 31;
    *(uint4*)(sA + row * LD + c8 * 8) = *(const uint4*)(A + (size_t)(i0 + row) * 256 + c8 * 8);
  }
  f32x4 z = {0.f, 0.f, 0.f, 0.f};
  f32x4 acc[16];
  #pragma unroll
  for (int f = 0; f < 16; ++f) acc[f] = z;
  bf16x8 af[8];
  for (int nc = 0; nc < 8; ++nc) {
    if (nc) __syncthreads();
    #pragma unroll
    for (int p = 0; p < 4; ++p) {
      int q = p * 256 + tid; int row = q >> 5, c8 = q & 31;
      *(uint4*)(sB + row * LD + c8 * 8) =
          *(const uint4*)(Bt + (size_t)(half * 256 + nc * NC + row) * 256 + c8 * 8);
    }
    __syncthreads();
    if (nc == 0) {
      #pragma unroll
      for (int kk = 0; kk < 8; ++kk) af[kk] = ldb8(sA + (w * 16 + l16) * LD + kk * 32 + quad * 8);
    }
    #pragma unroll
    for (int nb = 0; nb < 2; ++nb) {
      int f = nc * 2 + nb;
      #pragma unroll
      for (int kk = 0; kk < 8; ++kk) {
        bf16x8 bfr = ldb8(sB + (nb * 16 + l16) * LD + kk * 32 + quad * 8);
        acc[f] = MFMA16(af[kk], bfr, acc[f]);
      }
    }
  }
  #pragma unroll
  for (int f = 0; f < 16; ++f) {
    int col = f * 16 + l16;
    float bv = bias[half * 256 + col];
    if (half == 0) {
      #pragma unroll
      for (int r = 0; r < 4; ++r) {
        int rowg = i0 + w * 16 + quad * 4 + r;
        float v = acc[f][r] + bv;
        v = v / (1.f + __expf(-v));     // silu
        Kb[(size_t)rowg * 256 + col] = f2bf(v);
      }
    } else {
      int rowg0 = i0 + w * 16 + quad * 4;
      int b = rowg0 >> 12, dd = rowg0 & 4095;
      ushort4 u;
      #pragma unroll
      for (int r = 0; r < 4; ++r) {
        float v = acc[f][r] + bv;
        v = v / (1.f + __expf(-v));
        ((u16*)&u)[r] = f2bf(v);
      }
      *(ushort4*)(Vt + ((size_t)(b * 256 + col)) * 4096 + dd) = u;   // 4 consecutive dd
    }
  }
}

// ---------- Q: [b][i][o] = (sum_c y[b][c][i]*qw[o][c] + qb[o])*dww[o]+dwb[o] ----------
__global__ __launch_bounds__(256) void k_gemm_q(const float* __restrict__ y, const u16* __restrict__ Qw,
    const float* __restrict__ qb, const float* __restrict__ dww, const float* __restrict__ dwb,
    u16* __restrict__ Qb) {
  __shared__ u16 sY[64 * 72];    // y^T tile: [i][c], built by transpose staging
  __shared__ u16 sB[256 * 72];   // qw rows [o][c-chunk]
  int tid = threadIdx.x, w = tid >> 6, lane = tid & 63, quad = lane >> 4, l16 = lane & 15;
  int b = blockIdx.x >> 6, i0 = (blockIdx.x & 63) * 64;
  f32x4 z = {0.f, 0.f, 0.f, 0.f};
  f32x4 acc[16];
  #pragma unroll
  for (int f = 0; f < 16; ++f) acc[f] = z;
  for (int kc = 0; kc < 4; ++kc) {
    if (kc) __syncthreads();
    {   // transpose-stage y[b][c][i] -> sY[i][c]
      int cl = tid >> 4;            // 0..15
      int il = (tid & 15) * 4;      // 0..60
      #pragma unroll
      for (int p = 0; p < 4; ++p) {
        int c = kc * 64 + p * 16 + cl;
        float4 v = *(const float4*)(y + ((size_t)(b * 256 + c)) * 4096 + i0 + il);
        sY[(il + 0) * 72 + p * 16 + cl] = f2bf(v.x);
        sY[(il + 1) * 72 + p * 16 + cl] = f2bf(v.y);
        sY[(il + 2) * 72 + p * 16 + cl] = f2bf(v.z);
        sY[(il + 3) * 72 + p * 16 + cl] = f2bf(v.w);
      }
    }
    #pragma unroll
    for (int p = 0; p < 8; ++p) {
      int q = p * 256 + tid; int row = q >> 3, k8 = q & 7;
      *(uint4*)(sB + row * 72 + k8 * 8) = *(const uint4*)(Qw + (size_t)row * 256 + kc * 64 + k8 * 8);
    }
    __syncthreads();
    #pragma unroll
    for (int kk = 0; kk < 2; ++kk) {
      bf16x8 af = ldb8(sY + (w * 16 + l16) * 72 + kk * 32 + quad * 8);
      #pragma unroll
      for (int f = 0; f < 16; ++f) {
        bf16x8 bfr = ldb8(sB + (f * 16 + l16) * 72 + kk * 32 + quad * 8);
        acc[f] = MFMA16(af, bfr, acc[f]);
      }
    }
  }
  #pragma unroll
  for (int f = 0; f < 16; ++f) {
    int col = f * 16 + l16;
    float q0 = qb[col], sc = dww[col], dB = dwb[col];
    #pragma unroll
    for (int r = 0; r < 4; ++r) {
      int rowg = i0 + w * 16 + quad * 4 + r;
      float v = (acc[f][r] + q0) * sc + dB;
      Qb[((size_t)(b * 4096 + rowg)) * 256 + col] = f2bf(v);
    }
  }
}

// ---------- flash attention: Q[b][i][c] x K[b][d][c] -> softmax -> V^T[b][c][d] ----------
__global__ __launch_bounds__(256) void k_attn(const u16* __restrict__ Qb, const u16* __restrict__ Kb,
    const u16* __restrict__ Vt, u16* __restrict__ Hb) {
  __shared__ u16 sK[32 * 264];      // K tile [dd][c], padded
  __shared__ u16 sV[256 * 40];      // V^T tile [c][dd], padded
  __shared__ u16 sP[4 * 16 * 40];   // per-wave P bounce [row][dd]
  int tid = threadIdx.x, w = tid >> 6, lane = tid & 63, quad = lane >> 4, l16 = lane & 15;
  int b = blockIdx.x >> 6, i0 = (blockIdx.x & 63) * 64;
  // Q fragments resident (rows i0+w*16+l16, all 256 c)
  bf16x8 qf[8];
  {
    const u16* qrow = Qb + ((size_t)(b * 4096 + i0 + w * 16 + l16)) * 256;
    #pragma unroll
    for (int kk = 0; kk < 8; ++kk) qf[kk] = *(const bf16x8*)(qrow + kk * 32 + quad * 8);
  }
  f32x4 z = {0.f, 0.f, 0.f, 0.f};
  f32x4 oacc[16];
  #pragma unroll
  for (int f = 0; f < 16; ++f) oacc[f] = z;
  float m4[4] = {-1e30f, -1e30f, -1e30f, -1e30f};
  float l4[4] = {0.f, 0.f, 0.f, 0.f};
  u16* sPw = sP + w * (16 * 40);
  const u16* Kbase = Kb + (size_t)b * 4096 * 256;
  const u16* Vbase = Vt + (size_t)b * 256 * 4096;
  #pragma unroll 1
  for (int kt = 0; kt < 128; ++kt) {
    int dd0 = kt * 32;
    __syncthreads();
    #pragma unroll
    for (int p = 0; p < 4; ++p) {    // stage K tile 32x256
      int q = p * 256 + tid; int row = q >> 5, c8 = q & 31;
      *(uint4*)(sK + row * 264 + c8 * 8) = *(const uint4*)(Kbase + (size_t)(dd0 + row) * 256 + c8 * 8);
    }
    #pragma unroll
    for (int p = 0; p < 4; ++p) {    // stage V^T tile 256x32
      int q = p * 256 + tid; int c = q >> 2, d8 = q & 3;
      *(uint4*)(sV + c * 40 + d8 * 8) = *(const uint4*)(Vbase + (size_t)c * 4096 + dd0 + d8 * 8);
    }
    __syncthreads();
    f32x4 s0 = z, s1 = z;
    #pragma unroll
    for (int kk = 0; kk < 8; ++kk) {
      bf16x8 k0 = ldb8(sK + l16 * 264 + kk * 32 + quad * 8);
      bf16x8 k1 = ldb8(sK + (16 + l16) * 264 + kk * 32 + quad * 8);
      s0 = MFMA16(qf[kk], k0, s0);
      s1 = MFMA16(qf[kk], k1, s1);
    }
    float alpha[4];
    #pragma unroll
    for (int r = 0; r < 4; ++r) {
      float a = s0[r] * 0.0625f, c = s1[r] * 0.0625f;    // * C^-0.5
      float nm = fmaxf(m4[r], red_max16(fmaxf(a, c)));
      alpha[r] = __expf(m4[r] - nm);
      float p0 = __expf(a - nm), p1 = __expf(c - nm);
      l4[r] = l4[r] * alpha[r] + red_sum16(p0 + p1);
      m4[r] = nm;
      sPw[(quad * 4 + r) * 40 + l16]      = f2bf(p0);
      sPw[(quad * 4 + r) * 40 + 16 + l16] = f2bf(p1);
    }
    #pragma unroll
    for (int f = 0; f < 16; ++f) {
      oacc[f][0] *= alpha[0]; oacc[f][1] *= alpha[1];
      oacc[f][2] *= alpha[2]; oacc[f][3] *= alpha[3];
    }
    __syncthreads();   // P write -> P read (cross-lane) visibility
    bf16x8 pf = ldb8(sPw + l16 * 40 + quad * 8);
    #pragma unroll
    for (int f = 0; f < 16; ++f) {
      bf16x8 vf = ldb8(sV + (f * 16 + l16) * 40 + quad * 8);
      oacc[f] = MFMA16(pf, vf, oacc[f]);
    }
  }
  #pragma unroll
  for (int r = 0; r < 4; ++r) {
    float inv = 1.f / l4[r];
    u16* orow = Hb + ((size_t)(b * 4096 + i0 + w * 16 + quad * 4 + r)) * 256;
    #pragma unroll
    for (int f = 0; f < 16; ++f) orow[f * 16 + l16] = f2bf(oacc[f][r] * inv);
  }
}

// ---------- proj + residual: out[b][o][i] = y + pb[o] + sum_c pw[o][c]*H[b][i][c] ----------
__global__ __launch_bounds__(256) void k_proj(const u16* __restrict__ Hb, const u16* __restrict__ Pw,
    const float* __restrict__ pb, const float* __restrict__ y, float* __restrict__ out) {
  __shared__ u16 sA[64 * 136];
  __shared__ u16 sB[64 * 136];
  int tid = threadIdx.x, w = tid >> 6, lane = tid & 63, quad = lane >> 4, l16 = lane & 15;
  int i0 = blockIdx.x * 64, o0 = blockIdx.y * 64, b = blockIdx.z;
  f32x4 z = {0.f, 0.f, 0.f, 0.f};
  f32x4 acc[4] = {z, z, z, z};
  for (int kc = 0; kc < 2; ++kc) {
    if (kc) __syncthreads();
    #pragma unroll
    for (int p = 0; p < 4; ++p) {
      int q = p * 256 + tid; int row = q >> 4, c8 = q & 15;
      *(uint4*)(sA + row * 136 + c8 * 8) = *(const uint4*)(Pw + ((size_t)(o0 + row)) * 256 + kc * 128 + c8 * 8);
      *(uint4*)(sB + row * 136 + c8 * 8) =
          *(const uint4*)(Hb + ((size_t)(b * 4096 + i0 + row)) * 256 + kc * 128 + c8 * 8);
    }
    __syncthreads();
    #pragma unroll
    for (int kk = 0; kk < 4; ++kk) {
      bf16x8 af = ldb8(sA + (w * 16 + l16) * 136 + kk * 32 + quad * 8);
      #pragma unroll
      for (int nb = 0; nb < 4; ++nb) {
        bf16x8 bfr = ldb8(sB + (nb * 16 + l16) * 136 + kk * 32 + quad * 8);
        acc[nb] = MFMA16(af, bfr, acc[nb]);
      }
    }
  }
  #pragma unroll
  for (int nb = 0; nb < 4; ++nb) {
    #pragma unroll
    for (int r = 0; r < 4; ++r) {
      int og = o0 + w * 16 + quad * 4 + r;
      size_t idx = ((size_t)(b * 256 + og)) * 4096 + i0 + nb * 16 + l16;
      out[idx] = y[idx] + acc[nb][r] + pb[og];
    }
  }
}

extern "C" void kernel_launch(void* const* d_in, const int* in_sizes, int n_in,
                              void* d_out, int out_size, void* d_ws, size_t ws_size,
                              hipStream_t stream) {
  (void)in_sizes; (void)n_in; (void)out_size; (void)ws_size;
  const float* x     = (const float*)d_in[0];
  const float* y     = (const float*)d_in[1];
  const float* q_w   = (const float*)d_in[2];
  const float* q_b   = (const float*)d_in[3];
  const float* dw_w  = (const float*)d_in[4];
  const float* dw_b  = (const float*)d_in[5];
  const float* kv_w1 = (const float*)d_in[6];
  const float* kv_b1 = (const float*)d_in[7];
  const float* ln1_g = (const float*)d_in[8];
  const float* ln1_b = (const float*)d_in[9];
  const float* kv_w2 = (const float*)d_in[10];
  const float* kv_b2 = (const float*)d_in[11];
  const float* ln2_g = (const float*)d_in[12];
  const float* ln2_b = (const float*)d_in[13];
  const float* kv_w3 = (const float*)d_in[14];
  const float* kv_b3 = (const float*)d_in[15];
  const float* ln3_g = (const float*)d_in[16];
  const float* ln3_b = (const float*)d_in[17];
  const float* kv_w4 = (const float*)d_in[18];
  const float* kv_b4 = (const float*)d_in[19];
  const float* proj_w = (const float*)d_in[20];
  const float* proj_b = (const float*)d_in[21];
  float* out = (float*)d_out;
  unsigned char* ws = (unsigned char*)d_ws;

  // ws layout (bytes). Aliasing: T2<->Hb, T3<->Qb, T1 inside Kb region (all lifetime-disjoint).
  u16* Wt2 = (u16*)(ws + 0);            // [256][128] bf16,  64 KB
  u16* Wt3 = (u16*)(ws + 65536);        // [256][256] bf16, 128 KB
  u16* Wt4 = (u16*)(ws + 196608);       // [512][256] bf16, 256 KB
  u16* Qw  = (u16*)(ws + 458752);       // [256][256] bf16, 128 KB
  u16* Pww = (u16*)(ws + 589824);       // [256][256] bf16, 128 KB
  u16* T2  = (u16*)(ws + 1048576);      // [16384][256] bf16, 8 MB
  u16* Hb  = T2;
  u16* T3  = (u16*)(ws + 9437184);      // 8 MB
  u16* Qb  = T3;
  u16* Kb  = (u16*)(ws + 17825792);     // [4][4096][256] bf16, 8 MB
  u16* T1  = Kb;                        // [16384][128] bf16, 4 MB (dead before Kb written)
  u16* Vt  = (u16*)(ws + 26214400);     // [4][256][4096] bf16, 8 MB

  k_transpose_cvt<<<128, 256, 0, stream>>>(kv_w2, Wt2, 128, 256);
  k_transpose_cvt<<<256, 256, 0, stream>>>(kv_w3, Wt3, 256, 256);
  k_transpose_cvt<<<512, 256, 0, stream>>>(kv_w4, Wt4, 256, 512);
  k_cvt<<<256, 256, 0, stream>>>(q_w, Qw, 65536);
  k_cvt<<<256, 256, 0, stream>>>(proj_w, Pww, 65536);
  k_mlp1<<<4096, 256, 0, stream>>>(x, kv_w1, kv_b1, ln1_g, ln1_b, T1);
  k_gemm_ln<128, 64><<<256, 256, 0, stream>>>(T1, Wt2, kv_b2, ln2_g, ln2_b, T2);
  k_gemm_ln<256, 32><<<256, 256, 0, stream>>>(T2, Wt3, kv_b3, ln3_g, ln3_b, T3);
  k_gemm_silu<<<dim3(256, 2), 256, 0, stream>>>(T3, Wt4, kv_b4, Kb, Vt);
  k_gemm_q<<<256, 256, 0, stream>>>(y, Qw, q_b, dw_w, dw_b, Qb);
  k_attn<<<256, 256, 0, stream>>>(Qb, Kb, Vt, Hb);
  k_proj<<<dim3(64, 4, 4), 256, 0, stream>>>(Hb, Pww, proj_b, y, out);
}

// Round 2
// 360.638 us; speedup vs baseline: 1.2581x; 1.2581x over previous
//
#include <hip/hip_runtime.h>
#include <cstdint>
#include <cstddef>

using bf16   = __bf16;
using bf16x8 = __bf16 __attribute__((ext_vector_type(8)));
using f32x4  = float  __attribute__((ext_vector_type(4)));
using u16    = unsigned short;

#define MFMA16(a, b, c) __builtin_amdgcn_mfma_f32_16x16x32_bf16(a, b, c, 0, 0, 0)

__device__ __forceinline__ u16 f2bf(float f) {
  union { float f; unsigned u; } v; v.f = f;
  unsigned r = v.u + 0x7fffu + ((v.u >> 16) & 1u);
  return (u16)(r >> 16);
}
// cheap round-half-up bf16 (hot path only)
__device__ __forceinline__ u16 bfc(float f) {
  union { float f; unsigned u; } v; v.f = f;
  return (u16)((v.u + 0x8000u) >> 16);
}
__device__ __forceinline__ bf16x8 ldb8(const u16* p) { return *(const bf16x8*)p; }
__device__ __forceinline__ float red_max16(float v) {
  v = fmaxf(v, __shfl_xor(v, 1, 64)); v = fmaxf(v, __shfl_xor(v, 2, 64));
  v = fmaxf(v, __shfl_xor(v, 4, 64)); v = fmaxf(v, __shfl_xor(v, 8, 64));
  return v;
}
__device__ __forceinline__ float red_sum16(float v) {
  v += __shfl_xor(v, 1, 64); v += __shfl_xor(v, 2, 64);
  v += __shfl_xor(v, 4, 64); v += __shfl_xor(v, 8, 64);
  return v;
}

// C^-0.5 * log2(e): folded into Q so attn softmax runs in exp2 domain
#define QSCALE 0.09016844005556021f

// ---------- prep: all weight converts/transposes in ONE launch ----------
__global__ void k_prep(const float* __restrict__ kv_w2, const float* __restrict__ kv_w3,
                       const float* __restrict__ kv_w4, const float* __restrict__ q_w,
                       const float* __restrict__ proj_w,
                       u16* __restrict__ Wt2, u16* __restrict__ Wt3, u16* __restrict__ Wt4,
                       u16* __restrict__ Qw, u16* __restrict__ Pww) {
  int idx = blockIdx.x * 256 + threadIdx.x;
  if (idx < 32768) {                    // kv_w2 [128][256] -> Wt2 [256][128]
    int n = idx >> 7, k = idx & 127;
    Wt2[idx] = f2bf(kv_w2[k * 256 + n]);
  } else if (idx < 98304) {             // kv_w3 [256][256] -> Wt3 [256][256]
    int j = idx - 32768, n = j >> 8, k = j & 255;
    Wt3[j] = f2bf(kv_w3[k * 256 + n]);
  } else if (idx < 229376) {            // kv_w4 [256][512] -> Wt4 [512][256]
    int j = idx - 98304, n = j >> 8, k = j & 255;
    Wt4[j] = f2bf(kv_w4[k * 512 + n]);
  } else if (idx < 294912) {            // q_w [256][256] (already [o][c])
    int j = idx - 229376;
    Qw[j] = f2bf(q_w[j]);
  } else if (idx < 360448) {            // proj_w
    int j = idx - 294912;
    Pww[j] = f2bf(proj_w[j]);
  }
}

// ---------- MLP layer 1: T1[r][j] = leaky(LN(x[r]*w1[j]+b1[j])), j<128 ----------
__global__ __launch_bounds__(256) void k_mlp1(const float* __restrict__ x, const float* __restrict__ w1,
    const float* __restrict__ b1, const float* __restrict__ g, const float* __restrict__ bb,
    u16* __restrict__ T1) {
  int lane = threadIdx.x & 63;
  int r = blockIdx.x * 4 + (threadIdx.x >> 6);   // one wave per row
  float xv = x[r];
  float t0 = xv * w1[lane] + b1[lane];
  float t1 = xv * w1[lane + 64] + b1[lane + 64];
  float s = t0 + t1;
  #pragma unroll
  for (int m = 1; m <= 32; m <<= 1) s += __shfl_xor(s, m, 64);
  float mu = s * (1.f / 128.f);
  float d0 = t0 - mu, d1 = t1 - mu;
  float vv = d0 * d0 + d1 * d1;
  #pragma unroll
  for (int m = 1; m <= 32; m <<= 1) vv += __shfl_xor(vv, m, 64);
  float inv = rsqrtf(vv * (1.f / 128.f) + 1e-5f);
  float o0 = d0 * inv * g[lane] + bb[lane];
  float o1 = d1 * inv * g[lane + 64] + bb[lane + 64];
  o0 = o0 > 0.f ? o0 : 0.01f * o0;
  o1 = o1 > 0.f ? o1 : 0.01f * o1;
  T1[(size_t)r * 128 + lane]      = f2bf(o0);
  T1[(size_t)r * 128 + lane + 64] = f2bf(o1);
}

// ---------- GEMM (M=16384, N=256) + bias + LayerNorm(row) + leaky ----------
template<int K, int NC>
__global__ __launch_bounds__(256) void k_gemm_ln(const u16* __restrict__ A, const u16* __restrict__ Bt,
    const float* __restrict__ bias, const float* __restrict__ g, const float* __restrict__ bb,
    u16* __restrict__ out) {
  constexpr int LD = K + 8;
  constexpr int CPR = K / 8;
  __shared__ u16 sA[64 * LD];
  __shared__ u16 sB[NC * LD];
  int tid = threadIdx.x, w = tid >> 6, lane = tid & 63, quad = lane >> 4, l16 = lane & 15;
  int i0 = blockIdx.x * 64;
  #pragma unroll
  for (int p = 0; p < (64 * CPR) / 256; ++p) {
    int q = p * 256 + tid; int row = q / CPR, c8 = q - row * CPR;
    *(uint4*)(sA + row * LD + c8 * 8) = *(const uint4*)(A + (size_t)(i0 + row) * K + c8 * 8);
  }
  f32x4 z = {0.f, 0.f, 0.f, 0.f};
  f32x4 acc[16];
  #pragma unroll
  for (int f = 0; f < 16; ++f) acc[f] = z;
  bf16x8 af[K / 32];
  constexpr int NCH = 256 / NC;
  for (int nc = 0; nc < NCH; ++nc) {
    if (nc) __syncthreads();
    #pragma unroll
    for (int p = 0; p < (NC * CPR) / 256; ++p) {
      int q = p * 256 + tid; int row = q / CPR, c8 = q - row * CPR;
      *(uint4*)(sB + row * LD + c8 * 8) = *(const uint4*)(Bt + (size_t)(nc * NC + row) * K + c8 * 8);
    }
    __syncthreads();
    if (nc == 0) {
      #pragma unroll
      for (int kk = 0; kk < K / 32; ++kk) af[kk] = ldb8(sA + (w * 16 + l16) * LD + kk * 32 + quad * 8);
    }
    #pragma unroll
    for (int nb = 0; nb < NC / 16; ++nb) {
      int f = nc * (NC / 16) + nb;
      #pragma unroll
      for (int kk = 0; kk < K / 32; ++kk) {
        bf16x8 bfr = ldb8(sB + (nb * 16 + l16) * LD + kk * 32 + quad * 8);
        acc[f] = MFMA16(af[kk], bfr, acc[f]);
      }
    }
  }
  #pragma unroll
  for (int f = 0; f < 16; ++f) {
    float bv = bias[f * 16 + l16];
    acc[f][0] += bv; acc[f][1] += bv; acc[f][2] += bv; acc[f][3] += bv;
  }
  #pragma unroll
  for (int r = 0; r < 4; ++r) {
    float s = 0;
    #pragma unroll
    for (int f = 0; f < 16; ++f) s += acc[f][r];
    s = red_sum16(s);
    float mu = s * (1.f / 256.f);
    float vv = 0;
    #pragma unroll
    for (int f = 0; f < 16; ++f) { float d = acc[f][r] - mu; vv += d * d; }
    vv = red_sum16(vv);
    float inv = rsqrtf(vv * (1.f / 256.f) + 1e-5f);
    int rowg = i0 + w * 16 + quad * 4 + r;
    #pragma unroll
    for (int f = 0; f < 16; ++f) {
      int col = f * 16 + l16;
      float o = (acc[f][r] - mu) * inv * g[col] + bb[col];
      o = o > 0.f ? o : 0.01f * o;
      out[(size_t)rowg * 256 + col] = f2bf(o);
    }
  }
}

// ---------- MLP layer 4: GEMM + silu, K [b][d][c] and V^T [b][c][d] ----------
__global__ __launch_bounds__(256) void k_gemm_silu(const u16* __restrict__ A, const u16* __restrict__ Bt,
    const float* __restrict__ bias, u16* __restrict__ Kb, u16* __restrict__ Vt) {
  constexpr int LD = 264, NC = 32;
  __shared__ u16 sA[64 * LD];
  __shared__ u16 sB[NC * LD];
  int tid = threadIdx.x, w = tid >> 6, lane = tid & 63, quad = lane >> 4, l16 = lane & 15;
  int i0 = blockIdx.x * 64;
  int half = blockIdx.y;
  #pragma unroll
  for (int p = 0; p < 8; ++p) {
    int q = p * 256 + tid; int row = q >> 5, c8 = q & 31;
    *(uint4*)(sA + row * LD + c8 * 8) = *(const uint4*)(A + (size_t)(i0 + row) * 256 + c8 * 8);
  }
  f32x4 z = {0.f, 0.f, 0.f, 0.f};
  f32x4 acc[16];
  #pragma unroll
  for (int f = 0; f < 16; ++f) acc[f] = z;
  bf16x8 af[8];
  for (int nc = 0; nc < 8; ++nc) {
    if (nc) __syncthreads();
    #pragma unroll
    for (int p = 0; p < 4; ++p) {
      int q = p * 256 + tid; int row = q >> 5, c8 = q & 31;
      *(uint4*)(sB + row * LD + c8 * 8) =
          *(const uint4*)(Bt + (size_t)(half * 256 + nc * NC + row) * 256 + c8 * 8);
    }
    __syncthreads();
    if (nc == 0) {
      #pragma unroll
      for (int kk = 0; kk < 8; ++kk) af[kk] = ldb8(sA + (w * 16 + l16) * LD + kk * 32 + quad * 8);
    }
    #pragma unroll
    for (int nb = 0; nb < 2; ++nb) {
      int f = nc * 2 + nb;
      #pragma unroll
      for (int kk = 0; kk < 8; ++kk) {
        bf16x8 bfr = ldb8(sB + (nb * 16 + l16) * LD + kk * 32 + quad * 8);
        acc[f] = MFMA16(af[kk], bfr, acc[f]);
      }
    }
  }
  #pragma unroll
  for (int f = 0; f < 16; ++f) {
    int col = f * 16 + l16;
    float bv = bias[half * 256 + col];
    if (half == 0) {
      #pragma unroll
      for (int r = 0; r < 4; ++r) {
        int rowg = i0 + w * 16 + quad * 4 + r;
        float v = acc[f][r] + bv;
        v = v / (1.f + __expf(-v));
        Kb[(size_t)rowg * 256 + col] = f2bf(v);
      }
    } else {
      int rowg0 = i0 + w * 16 + quad * 4;
      int b = rowg0 >> 12, dd = rowg0 & 4095;
      ushort4 u;
      #pragma unroll
      for (int r = 0; r < 4; ++r) {
        float v = acc[f][r] + bv;
        v = v / (1.f + __expf(-v));
        ((u16*)&u)[r] = f2bf(v);
      }
      *(ushort4*)(Vt + ((size_t)(b * 256 + col)) * 4096 + dd) = u;
    }
  }
}

// ---------- Q: pre-scaled by QSCALE for exp2-domain softmax ----------
__global__ __launch_bounds__(256) void k_gemm_q(const float* __restrict__ y, const u16* __restrict__ Qw,
    const float* __restrict__ qb, const float* __restrict__ dww, const float* __restrict__ dwb,
    u16* __restrict__ Qb) {
  __shared__ u16 sY[64 * 72];
  __shared__ u16 sB[256 * 72];
  int tid = threadIdx.x, w = tid >> 6, lane = tid & 63, quad = lane >> 4, l16 = lane & 15;
  int b = blockIdx.x >> 6, i0 = (blockIdx.x & 63) * 64;
  f32x4 z = {0.f, 0.f, 0.f, 0.f};
  f32x4 acc[16];
  #pragma unroll
  for (int f = 0; f < 16; ++f) acc[f] = z;
  for (int kc = 0; kc < 4; ++kc) {
    if (kc) __syncthreads();
    {
      int cl = tid >> 4;
      int il = (tid & 15) * 4;
      #pragma unroll
      for (int p = 0; p < 4; ++p) {
        int c = kc * 64 + p * 16 + cl;
        float4 v = *(const float4*)(y + ((size_t)(b * 256 + c)) * 4096 + i0 + il);
        sY[(il + 0) * 72 + p * 16 + cl] = f2bf(v.x);
        sY[(il + 1) * 72 + p * 16 + cl] = f2bf(v.y);
        sY[(il + 2) * 72 + p * 16 + cl] = f2bf(v.z);
        sY[(il + 3) * 72 + p * 16 + cl] = f2bf(v.w);
      }
    }
    #pragma unroll
    for (int p = 0; p < 8; ++p) {
      int q = p * 256 + tid; int row = q >> 3, k8 = q & 7;
      *(uint4*)(sB + row * 72 + k8 * 8) = *(const uint4*)(Qw + (size_t)row * 256 + kc * 64 + k8 * 8);
    }
    __syncthreads();
    #pragma unroll
    for (int kk = 0; kk < 2; ++kk) {
      bf16x8 af = ldb8(sY + (w * 16 + l16) * 72 + kk * 32 + quad * 8);
      #pragma unroll
      for (int f = 0; f < 16; ++f) {
        bf16x8 bfr = ldb8(sB + (f * 16 + l16) * 72 + kk * 32 + quad * 8);
        acc[f] = MFMA16(af, bfr, acc[f]);
      }
    }
  }
  #pragma unroll
  for (int f = 0; f < 16; ++f) {
    int col = f * 16 + l16;
    float q0 = qb[col], sc = dww[col], dB = dwb[col];
    #pragma unroll
    for (int r = 0; r < 4; ++r) {
      int rowg = i0 + w * 16 + quad * 4 + r;
      float v = ((acc[f][r] + q0) * sc + dB) * QSCALE;
      Qb[((size_t)(b * 4096 + rowg)) * 256 + col] = f2bf(v);
    }
  }
}

// ---------- flash attention v2 ----------
// 512 blocks: [b][32-row q-tile]. Waves: rg = w&1 (rows rg*16..), kh = w>>1 (key half).
// Frozen-m one-pass softmax (m fixed at tile-0 row max; exp2 domain, scale folded into Q).
// End-of-block LDS merge of the two key-half partials.
__global__ __launch_bounds__(256, 2) void k_attn(const u16* __restrict__ Qb, const u16* __restrict__ Kb,
    const u16* __restrict__ Vt, u16* __restrict__ Hb) {
  __shared__ char smem[79872];
  u16* sK = (u16*)smem;              // [2][32][264]
  u16* sV = (u16*)(smem + 33792);    // [2][256][40]
  u16* sP = (u16*)(smem + 74752);    // [4][16][40]
  int tid = threadIdx.x, w = tid >> 6, lane = tid & 63, quad = lane >> 4, l16 = lane & 15;
  int b = blockIdx.x >> 7, i0 = (blockIdx.x & 127) * 32;
  int rg = w & 1, kh = w >> 1;

  bf16x8 qf[8];
  {
    const u16* qrow = Qb + ((size_t)(b * 4096 + i0 + rg * 16 + l16)) * 256;
    #pragma unroll
    for (int kk = 0; kk < 8; ++kk) qf[kk] = ldb8(qrow + kk * 32 + quad * 8);
  }
  f32x4 z = {0.f, 0.f, 0.f, 0.f};
  f32x4 oacc[16];
  #pragma unroll
  for (int f = 0; f < 16; ++f) oacc[f] = z;
  float m2[4] = {0.f, 0.f, 0.f, 0.f};
  float l4[4] = {0.f, 0.f, 0.f, 0.f};
  u16* sPw = sP + w * 640;
  const u16* Kb0 = Kb + (size_t)b * 4096 * 256;
  const u16* Kb1 = Kb0 + (size_t)2048 * 256;
  const u16* Vb0 = Vt + (size_t)b * 256 * 4096;
  const u16* Vb1 = Vb0 + 2048;
  const u16* sKw = sK + kh * 8448;
  const u16* sVw = sV + kh * 10240;

  #pragma unroll 1
  for (int kt = 0; kt < 64; ++kt) {
    int dd0 = kt * 32;
    __syncthreads();
    // stage K tiles (both halves), 32x256 each, fully coalesced
    {
      const u16* kb0 = Kb0 + (size_t)dd0 * 256;
      const u16* kb1 = Kb1 + (size_t)dd0 * 256;
      #pragma unroll
      for (int p = 0; p < 4; ++p) {
        int q = p * 256 + tid; int row = q >> 5, c8 = q & 31;
        *(uint4*)(sK + row * 264 + c8 * 8)        = *(const uint4*)(kb0 + row * 256 + c8 * 8);
        *(uint4*)(sK + 8448 + row * 264 + c8 * 8) = *(const uint4*)(kb1 + row * 256 + c8 * 8);
      }
    }
    // stage V^T tiles (both halves), 256x32 each
    {
      const u16* vb0 = Vb0 + dd0;
      const u16* vb1 = Vb1 + dd0;
      #pragma unroll
      for (int p = 0; p < 4; ++p) {
        int q = p * 256 + tid; int c = q >> 2, d8 = q & 3;
        *(uint4*)(sV + c * 40 + d8 * 8)         = *(const uint4*)(vb0 + (size_t)c * 4096 + d8 * 8);
        *(uint4*)(sV + 10240 + c * 40 + d8 * 8) = *(const uint4*)(vb1 + (size_t)c * 4096 + d8 * 8);
      }
    }
    __syncthreads();
    // QK^T for this wave's 16 rows x 32 keys (exp2 domain, Q pre-scaled)
    f32x4 s0 = z, s1 = z;
    #pragma unroll
    for (int kk = 0; kk < 8; ++kk) {
      bf16x8 k0 = ldb8(sKw + l16 * 264 + kk * 32 + quad * 8);
      bf16x8 k1 = ldb8(sKw + (16 + l16) * 264 + kk * 32 + quad * 8);
      s0 = MFMA16(qf[kk], k0, s0);
      s1 = MFMA16(qf[kk], k1, s1);
    }
    if (kt == 0) {
      #pragma unroll
      for (int r = 0; r < 4; ++r) m2[r] = red_max16(fmaxf(s0[r], s1[r]));
    }
    #pragma unroll
    for (int r = 0; r < 4; ++r) {
      float p0 = exp2f(s0[r] - m2[r]);
      float p1 = exp2f(s1[r] - m2[r]);
      l4[r] += p0 + p1;
      sPw[(quad * 4 + r) * 40 + l16]      = bfc(p0);
      sPw[(quad * 4 + r) * 40 + 16 + l16] = bfc(p1);
    }
    // per-wave P bounce: ds ops are wave-ordered; explicit wait instead of a barrier
    asm volatile("s_waitcnt lgkmcnt(0)" ::: "memory");
    bf16x8 pf = ldb8(sPw + l16 * 40 + quad * 8);
    #pragma unroll
    for (int f = 0; f < 16; ++f) {
      bf16x8 vf = ldb8(sVw + (f * 16 + l16) * 40 + quad * 8);
      oacc[f] = MFMA16(pf, vf, oacc[f]);
    }
  }
  // finalize l (was per-lane partial), then merge key-halves via LDS
  #pragma unroll
  for (int r = 0; r < 4; ++r) l4[r] = red_sum16(l4[r]);
  __syncthreads();
  float* mO  = (float*)smem;           // [32][256]
  float* mlm = (float*)(smem + 32768); // [32][2]
  if (kh == 1) {
    #pragma unroll
    for (int f = 0; f < 16; ++f)
      #pragma unroll
      for (int r = 0; r < 4; ++r)
        mO[(rg * 16 + quad * 4 + r) * 256 + f * 16 + l16] = oacc[f][r];
    if (l16 == 0) {
      #pragma unroll
      for (int r = 0; r < 4; ++r) {
        mlm[(rg * 16 + quad * 4 + r) * 2]     = l4[r];
        mlm[(rg * 16 + quad * 4 + r) * 2 + 1] = m2[r];
      }
    }
  }
  __syncthreads();
  if (kh == 0) {
    #pragma unroll
    for (int r = 0; r < 4; ++r) {
      int rowl = rg * 16 + quad * 4 + r;
      float lb = mlm[rowl * 2], mb = mlm[rowl * 2 + 1];
      float M = fmaxf(m2[r], mb);
      float fa = exp2f(m2[r] - M), fb = exp2f(mb - M);
      float inv = 1.f / (l4[r] * fa + lb * fb);
      u16* orow = Hb + ((size_t)(b * 4096 + i0 + rowl)) * 256;
      #pragma unroll
      for (int f = 0; f < 16; ++f) {
        float ov = oacc[f][r] * fa + mO[rowl * 256 + f * 16 + l16] * fb;
        orow[f * 16 + l16] = f2bf(ov * inv);
      }
    }
  }
}

// ---------- proj + residual ----------
__global__ __launch_bounds__(256) void k_proj(const u16* __restrict__ Hb, const u16* __restrict__ Pw,
    const float* __restrict__ pb, const float* __restrict__ y, float* __restrict__ out) {
  __shared__ u16 sA[64 * 136];
  __shared__ u16 sB[64 * 136];
  int tid = threadIdx.x, w = tid >> 6, lane = tid & 63, quad = lane >> 4, l16 = lane & 15;
  int i0 = blockIdx.x * 64, o0 = blockIdx.y * 64, b = blockIdx.z;
  f32x4 z = {0.f, 0.f, 0.f, 0.f};
  f32x4 acc[4] = {z, z, z, z};
  for (int kc = 0; kc < 2; ++kc) {
    if (kc) __syncthreads();
    #pragma unroll
    for (int p = 0; p < 4; ++p) {
      int q = p * 256 + tid; int row = q >> 4, c8 = q & 15;
      *(uint4*)(sA + row * 136 + c8 * 8) = *(const uint4*)(Pw + ((size_t)(o0 + row)) * 256 + kc * 128 + c8 * 8);
      *(uint4*)(sB + row * 136 + c8 * 8) =
          *(const uint4*)(Hb + ((size_t)(b * 4096 + i0 + row)) * 256 + kc * 128 + c8 * 8);
    }
    __syncthreads();
    #pragma unroll
    for (int kk = 0; kk < 4; ++kk) {
      bf16x8 af = ldb8(sA + (w * 16 + l16) * 136 + kk * 32 + quad * 8);
      #pragma unroll
      for (int nb = 0; nb < 4; ++nb) {
        bf16x8 bfr = ldb8(sB + (nb * 16 + l16) * 136 + kk * 32 + quad * 8);
        acc[nb] = MFMA16(af, bfr, acc[nb]);
      }
    }
  }
  #pragma unroll
  for (int nb = 0; nb < 4; ++nb) {
    #pragma unroll
    for (int r = 0; r < 4; ++r) {
      int og = o0 + w * 16 + quad * 4 + r;
      size_t idx = ((size_t)(b * 256 + og)) * 4096 + i0 + nb * 16 + l16;
      out[idx] = y[idx] + acc[nb][r] + pb[og];
    }
  }
}

extern "C" void kernel_launch(void* const* d_in, const int* in_sizes, int n_in,
                              void* d_out, int out_size, void* d_ws, size_t ws_size,
                              hipStream_t stream) {
  (void)in_sizes; (void)n_in; (void)out_size; (void)ws_size;
  const float* x     = (const float*)d_in[0];
  const float* y     = (const float*)d_in[1];
  const float* q_w   = (const float*)d_in[2];
  const float* q_b   = (const float*)d_in[3];
  const float* dw_w  = (const float*)d_in[4];
  const float* dw_b  = (const float*)d_in[5];
  const float* kv_w1 = (const float*)d_in[6];
  const float* kv_b1 = (const float*)d_in[7];
  const float* ln1_g = (const float*)d_in[8];
  const float* ln1_b = (const float*)d_in[9];
  const float* kv_w2 = (const float*)d_in[10];
  const float* kv_b2 = (const float*)d_in[11];
  const float* ln2_g = (const float*)d_in[12];
  const float* ln2_b = (const float*)d_in[13];
  const float* kv_w3 = (const float*)d_in[14];
  const float* kv_b3 = (const float*)d_in[15];
  const float* ln3_g = (const float*)d_in[16];
  const float* ln3_b = (const float*)d_in[17];
  const float* kv_w4 = (const float*)d_in[18];
  const float* kv_b4 = (const float*)d_in[19];
  const float* proj_w = (const float*)d_in[20];
  const float* proj_b = (const float*)d_in[21];
  float* out = (float*)d_out;
  unsigned char* ws = (unsigned char*)d_ws;

  u16* Wt2 = (u16*)(ws + 0);
  u16* Wt3 = (u16*)(ws + 65536);
  u16* Wt4 = (u16*)(ws + 196608);
  u16* Qw  = (u16*)(ws + 458752);
  u16* Pww = (u16*)(ws + 589824);
  u16* T2  = (u16*)(ws + 1048576);
  u16* Hb  = T2;
  u16* T3  = (u16*)(ws + 9437184);
  u16* Qb  = T3;
  u16* Kb  = (u16*)(ws + 17825792);
  u16* T1  = Kb;
  u16* Vt  = (u16*)(ws + 26214400);

  k_prep<<<1408, 256, 0, stream>>>(kv_w2, kv_w3, kv_w4, q_w, proj_w, Wt2, Wt3, Wt4, Qw, Pww);
  k_mlp1<<<4096, 256, 0, stream>>>(x, kv_w1, kv_b1, ln1_g, ln1_b, T1);
  k_gemm_ln<128, 64><<<256, 256, 0, stream>>>(T1, Wt2, kv_b2, ln2_g, ln2_b, T2);
  k_gemm_ln<256, 32><<<256, 256, 0, stream>>>(T2, Wt3, kv_b3, ln3_g, ln3_b, T3);
  k_gemm_silu<<<dim3(256, 2), 256, 0, stream>>>(T3, Wt4, kv_b4, Kb, Vt);
  k_gemm_q<<<256, 256, 0, stream>>>(y, Qw, q_b, dw_w, dw_b, Qb);
  k_attn<<<512, 256, 0, stream>>>(Qb, Kb, Vt, Hb);
  k_proj<<<dim3(64, 4, 4), 256, 0, stream>>>(Hb, Pww, proj_b, y, out);
}